// Round 14
// baseline (601.576 us; speedup 1.0000x reference)
//
#include <hip/hip_runtime.h>
#include <hip/hip_bf16.h>
#include <cmath>

constexpr int NB = 4096;   // batch
constexpr int NH = 1024;   // hidden
constexpr int NE = 8;      // experts
constexpr int NF = 4096;   // dff
constexpr int NG = 512;    // gate hidden (H/2)
constexpr float THRESH = 0.1f;
constexpr int PAD_ROWS = 128;
constexpr size_t MAXS = (size_t)2 * NB;        // <= 8192 routed slots
constexpr size_t ROWS = MAXS + PAD_ROWS;       // padded (A-row reads clamped)
constexpr int AMAX = (int)ROWS - 1;

// Established (rounds 0-13):
//   ALL inputs f32 C-order positional. d_out f32 [output(B,H) | gate_w(B,E)].
//   ws_size >= ~256 MiB (R11 layout fits). ~All top-2 pass threshold.
//   R13: FETCH -40% but dur +20% -> GEMM is barrier-drain latency-bound,
//   not BW-bound -> this round ports the 8-phase counted-vmcnt schedule.

typedef float  f32x4  __attribute__((ext_vector_type(4)));
typedef __bf16 bf16x8 __attribute__((ext_vector_type(8)));
typedef __bf16 bf16x4 __attribute__((ext_vector_type(4)));

typedef __attribute__((address_space(1))) void gvoid_t;
typedef __attribute__((address_space(3))) void svoid_t;

__device__ __forceinline__ void gl_lds16(const void* g, void* l)
{
    __builtin_amdgcn_global_load_lds((gvoid_t*)g, (svoid_t*)l, 16, 0, 0);
}

__device__ __forceinline__ float silu_f(float v) { return v / (1.f + expf(-v)); }

__global__ void k_sentinel(float* out, float code)
{
    if (threadIdx.x == 0 && blockIdx.x == 0) out[0] = code;
}

// ---------------------------------------------------------------------------
// Transpose+convert one weight family: in f32 [e][R][C] -> out bf16 [e][C][R]
// ---------------------------------------------------------------------------
__global__ __launch_bounds__(256) void k_tconv(
    const float* __restrict__ in, __bf16* __restrict__ out, int R, int C)
{
    __shared__ float t[64][65];
    const int e = blockIdx.z;
    const float* I = in + (size_t)e * R * C;
    __bf16* O = out + (size_t)e * R * C;
    const int r0 = blockIdx.y * 64, c0 = blockIdx.x * 64;
    const int tid = threadIdx.x;
#pragma unroll
    for (int i = 0; i < 16; i++) {
        int idx = tid + i * 256;
        int r = idx >> 6, c = idx & 63;
        t[r][c] = I[(size_t)(r0 + r) * C + c0 + c];
    }
    __syncthreads();
#pragma unroll
    for (int i = 0; i < 16; i++) {
        int idx = tid + i * 256;
        int c = idx >> 6, r = idx & 63;
        O[(size_t)(c0 + c) * R + r0 + r] = (__bf16)t[r][c];
    }
}

// ---------------------------------------------------------------------------
// Gate GEMM: hidden = silu(x @ gate_w1 + gate_b1)   (f32 exact)
// ---------------------------------------------------------------------------
__global__ __launch_bounds__(256) void k_gate(
    const float* __restrict__ x, const float* __restrict__ w1,
    const float* __restrict__ b1, float* __restrict__ hidden)
{
    __shared__ float As[16][68];
    __shared__ float Bs[16][64];
    const int tid = threadIdx.x;
    const int r0 = blockIdx.y * 64, c0 = blockIdx.x * 64;
    const int tx = tid & 15, ty = tid >> 4;
    float acc[4][4] = {};
    for (int k0 = 0; k0 < NH; k0 += 16) {
#pragma unroll
        for (int i = 0; i < 4; i++) {
            int e = tid + i * 256;
            int m = e >> 4, kk = e & 15;
            As[kk][m] = x[(size_t)(r0 + m) * NH + k0 + kk];
        }
#pragma unroll
        for (int i = 0; i < 4; i++) {
            int e = tid + i * 256;
            int kk = e >> 6, n = e & 63;
            Bs[kk][n] = w1[(size_t)(k0 + kk) * NG + c0 + n];
        }
        __syncthreads();
#pragma unroll
        for (int kk = 0; kk < 16; kk++) {
            f32x4 a = *(const f32x4*)&As[kk][ty * 4];
            f32x4 b = *(const f32x4*)&Bs[kk][tx * 4];
#pragma unroll
            for (int i = 0; i < 4; i++)
#pragma unroll
                for (int j = 0; j < 4; j++)
                    acc[i][j] = fmaf(a[i], b[j], acc[i][j]);
        }
        __syncthreads();
    }
#pragma unroll
    for (int i = 0; i < 4; i++) {
        int row = r0 + ty * 4 + i;
        f32x4 o;
#pragma unroll
        for (int j = 0; j < 4; j++)
            o[j] = silu_f(acc[i][j] + b1[c0 + tx * 4 + j]);
        *(f32x4*)&hidden[(size_t)row * NG + c0 + tx * 4] = o;
    }
}

// ---------------------------------------------------------------------------
// Router: softmax -> top2 -> threshold -> per-expert slot lists
// ---------------------------------------------------------------------------
__global__ __launch_bounds__(64) void k_router(
    const float* __restrict__ hidden, const float* __restrict__ w2,
    const float* __restrict__ b2, float* __restrict__ gw_out,
    int* __restrict__ count, int* __restrict__ slot_row,
    float* __restrict__ slot_w, float* __restrict__ row_total,
    int* __restrict__ row_fired)
{
    const int r = blockIdx.x;
    const int l = threadIdx.x;
    float pe[NE] = {};
    for (int k = l; k < NG; k += 64) {
        float h = hidden[(size_t)r * NG + k];
        const float* wr = w2 + (size_t)k * NE;
#pragma unroll
        for (int e = 0; e < NE; e++) pe[e] += h * wr[e];
    }
#pragma unroll
    for (int e = 0; e < NE; e++) {
#pragma unroll
        for (int m = 1; m < 64; m <<= 1) pe[e] += __shfl_xor(pe[e], m);
    }
    float logit[NE];
    float mx = -1e30f;
#pragma unroll
    for (int e = 0; e < NE; e++) { logit[e] = pe[e] + b2[e]; mx = fmaxf(mx, logit[e]); }
    float w[NE], s = 0.f;
#pragma unroll
    for (int e = 0; e < NE; e++) { w[e] = expf(logit[e] - mx); s += w[e]; }
    float inv = 1.f / s;
#pragma unroll
    for (int e = 0; e < NE; e++) w[e] *= inv;
    if (l < NE) gw_out[(size_t)r * NE + l] = w[l];

    int i1 = 0; float v1 = w[0];
#pragma unroll
    for (int e = 1; e < NE; e++) if (w[e] > v1) { v1 = w[e]; i1 = e; }
    int i2 = -1; float v2 = -1.f;
#pragma unroll
    for (int e = 0; e < NE; e++) if (e != i1 && w[e] > v2) { v2 = w[e]; i2 = e; }

    bool k1 = v1 > THRESH, k2 = v2 > THRESH;
    float total = (k1 ? v1 : 0.f) + (k2 ? v2 : 0.f);
    if (l == 0) {
        row_total[r] = total;
        row_fired[r] = (total > 0.f) ? 1 : 0;
        if (k1) { int p = atomicAdd(&count[i1], 1); slot_row[i1 * NB + p] = r; slot_w[i1 * NB + p] = v1; }
        if (k2) { int p = atomicAdd(&count[i2], 1); slot_row[i2 * NB + p] = r; slot_w[i2 * NB + p] = v2; }
    }
}

__global__ void k_offsets(const int* __restrict__ count, int* __restrict__ offs)
{
    if (threadIdx.x == 0 && blockIdx.x == 0) {
        int s = 0;
        for (int e = 0; e < NE; e++) { offs[e] = s; s += count[e]; }
    }
}

// ---------------------------------------------------------------------------
// Compacted bf16 x gather: Xc[slot] = bf16(x[slot_row])
// ---------------------------------------------------------------------------
__global__ __launch_bounds__(256) void k_xc(
    const float* __restrict__ x, const int* __restrict__ count,
    const int* __restrict__ offs, const int* __restrict__ slot_row,
    __bf16* __restrict__ Xc)
{
    const int s = blockIdx.x;
    int e = 0;
#pragma unroll
    for (int i = 1; i < NE; i++) if (s >= offs[i]) e = i;
    if (s >= offs[NE - 1] + count[NE - 1]) return;
    const int r = slot_row[e * NB + (s - offs[e])];
    const float* src = x + (size_t)r * NH;
    __bf16* dst = Xc + (size_t)s * NH;
    const int t = threadIdx.x;
    f32x4 v = *(const f32x4*)(src + t * 4);
    bf16x4 o;
#pragma unroll
    for (int j = 0; j < 4; j++) o[j] = (__bf16)v[j];
    *(bf16x4*)(dst + t * 4) = o;
}

// ---------------------------------------------------------------------------
// 8-PHASE 256x256 routed GEMM (T3+T4+T5 port).
// 512 threads (8 waves, 2M x 4N), BK=64 as two k-halves of 32, LDS 128 KiB:
//   per operand 4 regions of 16KB = (tile-parity, k-half); even tiles buf0.
// Schedule per iteration (tiles t0=2I, t1=2I+1), 4 pairs of 2 phases:
//   pair(t0,ks0 | stage t1.k1), pair(t0,ks1 | stage t0+2.k0),
//   pair(t1,ks0 | stage t0+2.k1), pair(t1,ks1 | stage t0+3.k0)
// Every half staged 6 phases ahead of first read into a region whose last
// reader finished >=1 barrier earlier. Pair end: s_waitcnt vmcnt(8) + raw
// s_barrier (loads from pair Q retire at pair Q+2 end, read pair Q+3).
// Stage k-ADDRESS clamps at NT-1 but region parity follows the LOGICAL tile.
// ---------------------------------------------------------------------------
template<int ACT, int OM>
__global__ __launch_bounds__(512, 2) void k_gemm8(
    const __bf16* __restrict__ A, int lda,
    const __bf16* __restrict__ Wt, size_t wstride,
    const float* __restrict__ bias, int bstride,
    __bf16* __restrict__ outB, float* __restrict__ outF,
    int N, int Kd, int X,
    const int* __restrict__ count, const int* __restrict__ offs,
    const int* __restrict__ slot_row, const float* __restrict__ slot_w)
{
    extern __shared__ __align__(16) unsigned char lds[];   // 131072 B
    const int bx = blockIdx.x;
    const int e  = bx / X;
    const int n0 = (bx % X) * 256;
    const int cnt = count[e];
    const int row0 = blockIdx.y * 256;
    if (row0 >= cnt) return;
    const int off = offs[e];
    const __bf16* W = Wt + (size_t)e * wstride;
    const int tid = threadIdx.x;
    const int lane = tid & 63, wid = tid >> 6;
    const int wrow = wid >> 2, wcol = wid & 3;    // 2 x 4 wave grid
    const int arow0 = off + row0;

    unsigned char* sA = lds;             // 4 x 16KB regions
    unsigned char* sB = lds + 65536;

    f32x4 acc[8][4];
#pragma unroll
    for (int i = 0; i < 8; i++)
#pragma unroll
        for (int j = 0; j < 4; j++)
            acc[i][j] = (f32x4){0.f, 0.f, 0.f, 0.f};

    // stage one half-tile (2 gloads/thread). ta = addr tile (clamped),
    // tp = region parity tile (logical), kh = k-half.
    auto stage = [&](int isB, int ta, int tp, int kh) {
        unsigned char* base = (isB ? sB : sA) + ((((tp & 1) << 1) | kh) << 14);
#pragma unroll
        for (int i = 0; i < 2; i++) {
            int r = (wid * 2 + i) * 16 + (lane >> 2);
            int ck = (lane & 3) ^ (r & 3);
            size_t col = (size_t)(ta * 64 + kh * 32 + ck * 8);
            const __bf16* g;
            if (isB) g = W + (size_t)(n0 + r) * Kd + col;
            else {
                int rg = arow0 + r; if (rg > AMAX) rg = AMAX;
                g = A + (size_t)rg * lda + col;
            }
            gl_lds16(g, base + (wid * 2 + i) * 1024 + lane * 16);
        }
    };
    auto rdA = [&](int tt, int ks, int am) -> bf16x8 {
        int row = wrow * 128 + am * 16 + (lane & 15);
        const unsigned char* rg = sA + ((((tt & 1) << 1) | ks) << 14);
        return *(const bf16x8*)(rg + row * 64 + ((((lane >> 4)) ^ (row & 3)) << 4));
    };
    auto rdB = [&](int tt, int ks, int fn) -> bf16x8 {
        int row = wcol * 64 + fn * 16 + (lane & 15);
        const unsigned char* rg = sB + ((((tt & 1) << 1) | ks) << 14);
        return *(const bf16x8*)(rg + row * 64 + ((((lane >> 4)) ^ (row & 3)) << 4));
    };

    auto pair = [&](int tt, int ks, int sa, int sp, int sk) {
        bf16x8 b[4], a[4];
#pragma unroll
        for (int f = 0; f < 4; f++) b[f] = rdB(tt, ks, f);
        // phase mq=0
#pragma unroll
        for (int f = 0; f < 4; f++) a[f] = rdA(tt, ks, f);
        stage(0, sa, sp, sk);                       // A half of next
        __builtin_amdgcn_s_setprio(1);
#pragma unroll
        for (int fm = 0; fm < 4; fm++)
#pragma unroll
            for (int fn = 0; fn < 4; fn++)
                acc[fm][fn] = __builtin_amdgcn_mfma_f32_16x16x32_bf16(
                    a[fm], b[fn], acc[fm][fn], 0, 0, 0);
        __builtin_amdgcn_s_setprio(0);
        // phase mq=1
#pragma unroll
        for (int f = 0; f < 4; f++) a[f] = rdA(tt, ks, 4 + f);
        stage(1, sa, sp, sk);                       // B half of next
        __builtin_amdgcn_s_setprio(1);
#pragma unroll
        for (int fm = 0; fm < 4; fm++)
#pragma unroll
            for (int fn = 0; fn < 4; fn++)
                acc[4 + fm][fn] = __builtin_amdgcn_mfma_f32_16x16x32_bf16(
                    a[fm], b[fn], acc[4 + fm][fn], 0, 0, 0);
        __builtin_amdgcn_s_setprio(0);
        asm volatile("s_waitcnt vmcnt(8)" ::: "memory");
        __builtin_amdgcn_s_barrier();
    };

    const int NT = Kd >> 6;                        // even (16 or 64)
    // prologue: t0.k0, t0.k1, t1.k0  (A+B each)
    stage(0, 0, 0, 0); stage(1, 0, 0, 0);
    stage(0, 0, 0, 1); stage(1, 0, 0, 1);
    stage(0, 1, 1, 0); stage(1, 1, 1, 0);
    asm volatile("s_waitcnt vmcnt(8)" ::: "memory");
    __builtin_amdgcn_s_barrier();

    for (int I = 0; I < NT / 2; ++I) {
        const int t0 = 2 * I, t1 = t0 + 1;
        const int a2 = (t0 + 2 < NT) ? t0 + 2 : NT - 1;   // addr clamp
        const int a3 = (t0 + 3 < NT) ? t0 + 3 : NT - 1;
        pair(t0, 0, t1, t1, 1);          // stage t1.k1   -> (1,1)
        pair(t0, 1, a2, t0 + 2, 0);      // stage t0+2.k0 -> (0,0)
        pair(t1, 0, a2, t0 + 2, 1);      // stage t0+2.k1 -> (0,1)
        pair(t1, 1, a3, t0 + 3, 0);      // stage t0+3.k0 -> (1,0)
    }
    asm volatile("s_waitcnt vmcnt(0)" ::: "memory");   // drain before exit

    // ---- epilogue ----
    const int q = lane >> 4, cl = lane & 15;
#pragma unroll
    for (int am = 0; am < 8; am++) {
#pragma unroll
        for (int r = 0; r < 4; r++) {
            int srow = row0 + wrow * 128 + am * 16 + q * 4 + r;
            if (srow >= cnt) continue;
            if (OM == 0) {
#pragma unroll
                for (int fn = 0; fn < 4; fn++) {
                    int col = n0 + wcol * 64 + fn * 16 + cl;
                    float vv = acc[am][fn][r] + bias[(size_t)e * bstride + col];
                    if (ACT) vv = silu_f(vv);
                    outB[(size_t)(off + srow) * N + col] = (__bf16)vv;
                }
            } else {
                int grow = slot_row[e * NB + srow];
                float wsl = slot_w[e * NB + srow];
#pragma unroll
                for (int fn = 0; fn < 4; fn++) {
                    int col = n0 + wcol * 64 + fn * 16 + cl;
                    atomicAdd(&outF[(size_t)grow * NH + col], wsl * acc[am][fn][r]);
                }
            }
        }
    }
}

// ---------------------------------------------------------------------------
// Finalize IN-PLACE: out = fired ? a*(out/t) + (1-a)*x : x
// ---------------------------------------------------------------------------
__global__ __launch_bounds__(256) void k_final(
    const float* __restrict__ x,
    const float* __restrict__ row_total, const int* __restrict__ row_fired,
    const float* __restrict__ blend, float* __restrict__ out)
{
    int idx = blockIdx.x * 256 + threadIdx.x;
    int r = idx >> 8;
    int c = (idx & 255) << 2;
    float alpha = 1.f / (1.f + expf(-blend[0]));
    f32x4 cb = *(const f32x4*)(out + (size_t)r * NH + c);
    f32x4 xv = *(const f32x4*)(x + (size_t)r * NH + c);
    int fired = row_fired[r];
    float inv_t = fired ? (1.f / row_total[r]) : 0.f;
    f32x4 o;
#pragma unroll
    for (int j = 0; j < 4; j++)
        o[j] = fired ? (alpha * (cb[j] * inv_t) + (1.f - alpha) * xv[j]) : xv[j];
    *(f32x4*)&out[(size_t)r * NH + c] = o;
}

// ---------------------------------------------------------------------------
extern "C" void kernel_launch(void* const* d_in, const int* in_sizes, int n_in,
                              void* d_out, int out_size, void* d_ws, size_t ws_size,
                              hipStream_t stream)
{
    float* out_main = (float*)d_out;
    float* gw_out   = (float*)d_out + (size_t)NB * NH;

    static const long long EXP[11] = {
        (long long)NB * NH, (long long)NH * NG, NG, (long long)NG * NE, NE,
        (long long)NE * NH * NF, (long long)NE * NF,
        (long long)NE * NF * NH, (long long)NE * NH,
        (long long)NE * NH * NH, 1
    };
    bool ok = (n_in == 11);
    if (ok)
        for (int i = 0; i < 11; i++)
            if ((long long)in_sizes[i] != EXP[i]) { ok = false; break; }
    if (!ok) {
        k_sentinel<<<1, 1, 0, stream>>>((float*)d_out, 2000.f + n_in);
        return;
    }

    const float* x    = (const float*)d_in[0];
    const float* gw1  = (const float*)d_in[1];
    const float* gb1  = (const float*)d_in[2];
    const float* gw2  = (const float*)d_in[3];
    const float* gb2  = (const float*)d_in[4];
    const float* ew1  = (const float*)d_in[5];
    const float* eb1  = (const float*)d_in[6];
    const float* ew2  = (const float*)d_in[7];
    const float* eb2  = (const float*)d_in[8];
    const float* pw   = (const float*)d_in[9];
    const float* blnd = (const float*)d_in[10];

    // ---- workspace layout (identical to R11, proven fits) ----
    size_t need = 0;
    size_t off_meta   = need;   need += 512;
    size_t off_srow   = need;   need += (size_t)NE * NB * 4;
    size_t off_sw     = need;   need += (size_t)NE * NB * 4;
    size_t off_total  = need;   need += (size_t)NB * 4;
    size_t off_fired  = need;   need += (size_t)NB * 4;
    size_t off_hidden = need;   need += (size_t)NB * NG * 4;
    size_t a_xc  = need;
    size_t a_h1  = a_xc + ROWS * NH * 2;
    size_t a_h2  = a_h1 + ROWS * NF * 2;
    size_t a_w1  = a_h2 + ROWS * NH * 2;
    size_t a_w2  = a_w1 + (size_t)NE * NH * NF * 2;
    size_t a_wp  = a_w2 + (size_t)NE * NF * NH * 2;
    size_t need_A = a_wp + (size_t)NE * NH * NH * 2;

    char* ws = (char*)d_ws;
    int*   count     = (int*)(ws + off_meta);
    int*   offs      = count + 8;
    int*   slot_row  = (int*)(ws + off_srow);
    float* slot_w    = (float*)(ws + off_sw);
    float* row_total = (float*)(ws + off_total);
    int*   row_fired = (int*)(ws + off_fired);
    float* hidden    = (float*)(ws + off_hidden);

    if (ws_size < need_A) {
        k_sentinel<<<1, 1, 0, stream>>>((float*)d_out,
                                        1000.f + (float)(ws_size >> 20));
        return;
    }
    __bf16* Xc  = (__bf16*)(ws + a_xc);
    __bf16* H1  = (__bf16*)(ws + a_h1);
    __bf16* H2  = (__bf16*)(ws + a_h2);
    __bf16* Wt1 = (__bf16*)(ws + a_w1);
    __bf16* Wt2 = (__bf16*)(ws + a_w2);
    __bf16* Wtp = (__bf16*)(ws + a_wp);

    // allow 128 KiB dynamic LDS (idempotent; ignore errors)
    (void)hipFuncSetAttribute((const void*)&k_gemm8<1, 0>,
        hipFuncAttributeMaxDynamicSharedMemorySize, 131072);
    (void)hipFuncSetAttribute((const void*)&k_gemm8<0, 0>,
        hipFuncAttributeMaxDynamicSharedMemorySize, 131072);
    (void)hipFuncSetAttribute((const void*)&k_gemm8<0, 1>,
        hipFuncAttributeMaxDynamicSharedMemorySize, 131072);

    hipMemsetAsync(count, 0, 512, stream);
    hipMemsetAsync(out_main, 0, (size_t)NB * NH * 4, stream);

    k_gate<<<dim3(NG / 64, NB / 64), 256, 0, stream>>>(x, gw1, gb1, hidden);
    k_router<<<dim3(NB), 64, 0, stream>>>(hidden, gw2, gb2, gw_out,
                                          count, slot_row, slot_w, row_total, row_fired);
    k_offsets<<<1, 1, 0, stream>>>(count, offs);

    k_tconv<<<dim3(NF / 64, NH / 64, NE), 256, 0, stream>>>(ew1, Wt1, NH, NF);
    k_tconv<<<dim3(NH / 64, NF / 64, NE), 256, 0, stream>>>(ew2, Wt2, NF, NH);
    k_tconv<<<dim3(NH / 64, NH / 64, NE), 256, 0, stream>>>(pw,  Wtp, NH, NH);
    k_xc<<<dim3((int)MAXS), 256, 0, stream>>>(x, count, offs, slot_row, Xc);

    // FFN1: H1 = silu(Xc @ ew1 + eb1)      X = NF/256 = 16
    k_gemm8<1, 0><<<dim3(16 * NE, NB / 256), 512, 131072, stream>>>(
        Xc, NH, Wt1, (size_t)NH * NF, eb1, NF,
        H1, nullptr, NF, NH, 16, count, offs, slot_row, slot_w);
    // FFN2: H2 = H1 @ ew2 + eb2            X = NH/256 = 4
    k_gemm8<0, 0><<<dim3(4 * NE, NB / 256), 512, 131072, stream>>>(
        H1, NF, Wt2, (size_t)NF * NH, eb2, NH,
        H2, nullptr, NH, NF, 4, count, offs, slot_row, slot_w);
    // PROJ: out += slot_w * (H2 @ pw)      X = 4
    k_gemm8<0, 1><<<dim3(4 * NE, NB / 256), 512, 131072, stream>>>(
        H2, NH, Wtp, (size_t)NH * NH, eb2 /*unused*/, 0,
        nullptr, out_main, NH, NH, 4, count, offs, slot_row, slot_w);

    k_final<<<dim3(NB * NH / 1024), 256, 0, stream>>>(x, row_total,
                                                      row_fired, blnd, out_main);
}

// Round 15
// 596.844 us; speedup vs baseline: 1.0079x; 1.0079x over previous
//
#include <hip/hip_runtime.h>
#include <hip/hip_bf16.h>
#include <cmath>

constexpr int NB = 4096;   // batch
constexpr int NH = 1024;   // hidden
constexpr int NE = 8;      // experts
constexpr int NF = 4096;   // dff
constexpr int NG = 512;    // gate hidden (H/2)
constexpr float THRESH = 0.1f;
constexpr int PAD_ROWS = 128;
constexpr size_t MAXS = (size_t)2 * NB;        // <= 8192 routed slots
constexpr size_t ROWS = MAXS + PAD_ROWS;       // padded (A-row reads clamped)
constexpr int AMAX = (int)ROWS - 1;

// Established (rounds 0-14):
//   ALL inputs f32 C-order positional. d_out f32 [output(B,H) | gate_w(B,E)].
//   ws_size >= ~256 MiB. ~All top-2 pass threshold.
//   R14: 8-phase port correct but 4-way LDS bank conflict (7.08M events) on
//   ds_read (bad swizzle for 64B rows). This round: s(row)=(row>>1)&3 fix.

typedef float  f32x4  __attribute__((ext_vector_type(4)));
typedef __bf16 bf16x8 __attribute__((ext_vector_type(8)));
typedef __bf16 bf16x4 __attribute__((ext_vector_type(4)));

typedef __attribute__((address_space(1))) void gvoid_t;
typedef __attribute__((address_space(3))) void svoid_t;

__device__ __forceinline__ void gl_lds16(const void* g, void* l)
{
    __builtin_amdgcn_global_load_lds((gvoid_t*)g, (svoid_t*)l, 16, 0, 0);
}

__device__ __forceinline__ float silu_f(float v) { return v / (1.f + expf(-v)); }

__global__ void k_sentinel(float* out, float code)
{
    if (threadIdx.x == 0 && blockIdx.x == 0) out[0] = code;
}

// ---------------------------------------------------------------------------
// Transpose+convert one weight family: in f32 [e][R][C] -> out bf16 [e][C][R]
// ---------------------------------------------------------------------------
__global__ __launch_bounds__(256) void k_tconv(
    const float* __restrict__ in, __bf16* __restrict__ out, int R, int C)
{
    __shared__ float t[64][65];
    const int e = blockIdx.z;
    const float* I = in + (size_t)e * R * C;
    __bf16* O = out + (size_t)e * R * C;
    const int r0 = blockIdx.y * 64, c0 = blockIdx.x * 64;
    const int tid = threadIdx.x;
#pragma unroll
    for (int i = 0; i < 16; i++) {
        int idx = tid + i * 256;
        int r = idx >> 6, c = idx & 63;
        t[r][c] = I[(size_t)(r0 + r) * C + c0 + c];
    }
    __syncthreads();
#pragma unroll
    for (int i = 0; i < 16; i++) {
        int idx = tid + i * 256;
        int c = idx >> 6, r = idx & 63;
        O[(size_t)(c0 + c) * R + r0 + r] = (__bf16)t[r][c];
    }
}

// ---------------------------------------------------------------------------
// Gate GEMM: hidden = silu(x @ gate_w1 + gate_b1)   (f32 exact)
// ---------------------------------------------------------------------------
__global__ __launch_bounds__(256) void k_gate(
    const float* __restrict__ x, const float* __restrict__ w1,
    const float* __restrict__ b1, float* __restrict__ hidden)
{
    __shared__ float As[16][68];
    __shared__ float Bs[16][64];
    const int tid = threadIdx.x;
    const int r0 = blockIdx.y * 64, c0 = blockIdx.x * 64;
    const int tx = tid & 15, ty = tid >> 4;
    float acc[4][4] = {};
    for (int k0 = 0; k0 < NH; k0 += 16) {
#pragma unroll
        for (int i = 0; i < 4; i++) {
            int e = tid + i * 256;
            int m = e >> 4, kk = e & 15;
            As[kk][m] = x[(size_t)(r0 + m) * NH + k0 + kk];
        }
#pragma unroll
        for (int i = 0; i < 4; i++) {
            int e = tid + i * 256;
            int kk = e >> 6, n = e & 63;
            Bs[kk][n] = w1[(size_t)(k0 + kk) * NG + c0 + n];
        }
        __syncthreads();
#pragma unroll
        for (int kk = 0; kk < 16; kk++) {
            f32x4 a = *(const f32x4*)&As[kk][ty * 4];
            f32x4 b = *(const f32x4*)&Bs[kk][tx * 4];
#pragma unroll
            for (int i = 0; i < 4; i++)
#pragma unroll
                for (int j = 0; j < 4; j++)
                    acc[i][j] = fmaf(a[i], b[j], acc[i][j]);
        }
        __syncthreads();
    }
#pragma unroll
    for (int i = 0; i < 4; i++) {
        int row = r0 + ty * 4 + i;
        f32x4 o;
#pragma unroll
        for (int j = 0; j < 4; j++)
            o[j] = silu_f(acc[i][j] + b1[c0 + tx * 4 + j]);
        *(f32x4*)&hidden[(size_t)row * NG + c0 + tx * 4] = o;
    }
}

// ---------------------------------------------------------------------------
// Router: softmax -> top2 -> threshold -> per-expert slot lists
// ---------------------------------------------------------------------------
__global__ __launch_bounds__(64) void k_router(
    const float* __restrict__ hidden, const float* __restrict__ w2,
    const float* __restrict__ b2, float* __restrict__ gw_out,
    int* __restrict__ count, int* __restrict__ slot_row,
    float* __restrict__ slot_w, float* __restrict__ row_total,
    int* __restrict__ row_fired)
{
    const int r = blockIdx.x;
    const int l = threadIdx.x;
    float pe[NE] = {};
    for (int k = l; k < NG; k += 64) {
        float h = hidden[(size_t)r * NG + k];
        const float* wr = w2 + (size_t)k * NE;
#pragma unroll
        for (int e = 0; e < NE; e++) pe[e] += h * wr[e];
    }
#pragma unroll
    for (int e = 0; e < NE; e++) {
#pragma unroll
        for (int m = 1; m < 64; m <<= 1) pe[e] += __shfl_xor(pe[e], m);
    }
    float logit[NE];
    float mx = -1e30f;
#pragma unroll
    for (int e = 0; e < NE; e++) { logit[e] = pe[e] + b2[e]; mx = fmaxf(mx, logit[e]); }
    float w[NE], s = 0.f;
#pragma unroll
    for (int e = 0; e < NE; e++) { w[e] = expf(logit[e] - mx); s += w[e]; }
    float inv = 1.f / s;
#pragma unroll
    for (int e = 0; e < NE; e++) w[e] *= inv;
    if (l < NE) gw_out[(size_t)r * NE + l] = w[l];

    int i1 = 0; float v1 = w[0];
#pragma unroll
    for (int e = 1; e < NE; e++) if (w[e] > v1) { v1 = w[e]; i1 = e; }
    int i2 = -1; float v2 = -1.f;
#pragma unroll
    for (int e = 0; e < NE; e++) if (e != i1 && w[e] > v2) { v2 = w[e]; i2 = e; }

    bool k1 = v1 > THRESH, k2 = v2 > THRESH;
    float total = (k1 ? v1 : 0.f) + (k2 ? v2 : 0.f);
    if (l == 0) {
        row_total[r] = total;
        row_fired[r] = (total > 0.f) ? 1 : 0;
        if (k1) { int p = atomicAdd(&count[i1], 1); slot_row[i1 * NB + p] = r; slot_w[i1 * NB + p] = v1; }
        if (k2) { int p = atomicAdd(&count[i2], 1); slot_row[i2 * NB + p] = r; slot_w[i2 * NB + p] = v2; }
    }
}

__global__ void k_offsets(const int* __restrict__ count, int* __restrict__ offs)
{
    if (threadIdx.x == 0 && blockIdx.x == 0) {
        int s = 0;
        for (int e = 0; e < NE; e++) { offs[e] = s; s += count[e]; }
    }
}

// ---------------------------------------------------------------------------
// Compacted bf16 x gather: Xc[slot] = bf16(x[slot_row])
// ---------------------------------------------------------------------------
__global__ __launch_bounds__(256) void k_xc(
    const float* __restrict__ x, const int* __restrict__ count,
    const int* __restrict__ offs, const int* __restrict__ slot_row,
    __bf16* __restrict__ Xc)
{
    const int s = blockIdx.x;
    int e = 0;
#pragma unroll
    for (int i = 1; i < NE; i++) if (s >= offs[i]) e = i;
    if (s >= offs[NE - 1] + count[NE - 1]) return;
    const int r = slot_row[e * NB + (s - offs[e])];
    const float* src = x + (size_t)r * NH;
    __bf16* dst = Xc + (size_t)s * NH;
    const int t = threadIdx.x;
    f32x4 v = *(const f32x4*)(src + t * 4);
    bf16x4 o;
#pragma unroll
    for (int j = 0; j < 4; j++) o[j] = (__bf16)v[j];
    *(bf16x4*)(dst + t * 4) = o;
}

// ---------------------------------------------------------------------------
// 8-PHASE 256x256 routed GEMM (T2-fixed: s(row)=(row>>1)&3 bank swizzle).
// Bank derivation (64B rows, 16B reads): quad = (4*(row&1) + chunk_eff) mod 8;
// chunk_eff = c ^ s(row). s=(row>>1)&3 makes (row&1, chunk_eff) bijective over
// row mod 8 -> 16 consecutive rows hit all 8 quad-sets exactly 2x (free).
// Rest identical to R14: 512 thr, 4x16KB regions/operand, counted vmcnt(8),
// raw s_barrier per pair, setprio around MFMA clusters.
// ---------------------------------------------------------------------------
template<int ACT, int OM>
__global__ __launch_bounds__(512, 2) void k_gemm8(
    const __bf16* __restrict__ A, int lda,
    const __bf16* __restrict__ Wt, size_t wstride,
    const float* __restrict__ bias, int bstride,
    __bf16* __restrict__ outB, float* __restrict__ outF,
    int N, int Kd, int X,
    const int* __restrict__ count, const int* __restrict__ offs,
    const int* __restrict__ slot_row, const float* __restrict__ slot_w)
{
    extern __shared__ __align__(16) unsigned char lds[];   // 131072 B
    const int bx = blockIdx.x;
    const int e  = bx / X;
    const int n0 = (bx % X) * 256;
    const int cnt = count[e];
    const int row0 = blockIdx.y * 256;
    if (row0 >= cnt) return;
    const int off = offs[e];
    const __bf16* W = Wt + (size_t)e * wstride;
    const int tid = threadIdx.x;
    const int lane = tid & 63, wid = tid >> 6;
    const int wrow = wid >> 2, wcol = wid & 3;    // 2 x 4 wave grid
    const int arow0 = off + row0;

    unsigned char* sA = lds;             // 4 x 16KB regions
    unsigned char* sB = lds + 65536;

    f32x4 acc[8][4];
#pragma unroll
    for (int i = 0; i < 8; i++)
#pragma unroll
        for (int j = 0; j < 4; j++)
            acc[i][j] = (f32x4){0.f, 0.f, 0.f, 0.f};

    // stage one half-tile (2 gloads/thread). ta = addr tile (clamped),
    // tp = region parity tile (logical), kh = k-half.
    auto stage = [&](int isB, int ta, int tp, int kh) {
        unsigned char* base = (isB ? sB : sA) + ((((tp & 1) << 1) | kh) << 14);
#pragma unroll
        for (int i = 0; i < 2; i++) {
            int r = (wid * 2 + i) * 16 + (lane >> 2);
            int ck = (lane & 3) ^ ((r >> 1) & 3);          // T2 fix
            size_t col = (size_t)(ta * 64 + kh * 32 + ck * 8);
            const __bf16* g;
            if (isB) g = W + (size_t)(n0 + r) * Kd + col;
            else {
                int rg = arow0 + r; if (rg > AMAX) rg = AMAX;
                g = A + (size_t)rg * lda + col;
            }
            gl_lds16(g, base + (wid * 2 + i) * 1024 + lane * 16);
        }
    };
    auto rdA = [&](int tt, int ks, int am) -> bf16x8 {
        int row = wrow * 128 + am * 16 + (lane & 15);
        const unsigned char* rg = sA + ((((tt & 1) << 1) | ks) << 14);
        return *(const bf16x8*)(rg + row * 64 +
                                ((((lane >> 4)) ^ ((row >> 1) & 3)) << 4));
    };
    auto rdB = [&](int tt, int ks, int fn) -> bf16x8 {
        int row = wcol * 64 + fn * 16 + (lane & 15);
        const unsigned char* rg = sB + ((((tt & 1) << 1) | ks) << 14);
        return *(const bf16x8*)(rg + row * 64 +
                                ((((lane >> 4)) ^ ((row >> 1) & 3)) << 4));
    };

    auto pair = [&](int tt, int ks, int sa, int sp, int sk) {
        bf16x8 b[4], a[4];
#pragma unroll
        for (int f = 0; f < 4; f++) b[f] = rdB(tt, ks, f);
        // phase mq=0
#pragma unroll
        for (int f = 0; f < 4; f++) a[f] = rdA(tt, ks, f);
        stage(0, sa, sp, sk);                       // A half of next
        __builtin_amdgcn_s_setprio(1);
#pragma unroll
        for (int fm = 0; fm < 4; fm++)
#pragma unroll
            for (int fn = 0; fn < 4; fn++)
                acc[fm][fn] = __builtin_amdgcn_mfma_f32_16x16x32_bf16(
                    a[fm], b[fn], acc[fm][fn], 0, 0, 0);
        __builtin_amdgcn_s_setprio(0);
        // phase mq=1
#pragma unroll
        for (int f = 0; f < 4; f++) a[f] = rdA(tt, ks, 4 + f);
        stage(1, sa, sp, sk);                       // B half of next
        __builtin_amdgcn_s_setprio(1);
#pragma unroll
        for (int fm = 0; fm < 4; fm++)
#pragma unroll
            for (int fn = 0; fn < 4; fn++)
                acc[4 + fm][fn] = __builtin_amdgcn_mfma_f32_16x16x32_bf16(
                    a[fm], b[fn], acc[4 + fm][fn], 0, 0, 0);
        __builtin_amdgcn_s_setprio(0);
        asm volatile("s_waitcnt vmcnt(8)" ::: "memory");
        __builtin_amdgcn_s_barrier();
    };

    const int NT = Kd >> 6;                        // even (16 or 64)
    // prologue: t0.k0, t0.k1, t1.k0  (A+B each)
    stage(0, 0, 0, 0); stage(1, 0, 0, 0);
    stage(0, 0, 0, 1); stage(1, 0, 0, 1);
    stage(0, 1, 1, 0); stage(1, 1, 1, 0);
    asm volatile("s_waitcnt vmcnt(8)" ::: "memory");
    __builtin_amdgcn_s_barrier();

    for (int I = 0; I < NT / 2; ++I) {
        const int t0 = 2 * I, t1 = t0 + 1;
        const int a2 = (t0 + 2 < NT) ? t0 + 2 : NT - 1;   // addr clamp
        const int a3 = (t0 + 3 < NT) ? t0 + 3 : NT - 1;
        pair(t0, 0, t1, t1, 1);          // stage t1.k1   -> (1,1)
        pair(t0, 1, a2, t0 + 2, 0);      // stage t0+2.k0 -> (0,0)
        pair(t1, 0, a2, t0 + 2, 1);      // stage t0+2.k1 -> (0,1)
        pair(t1, 1, a3, t0 + 3, 0);      // stage t0+3.k0 -> (1,0)
    }
    asm volatile("s_waitcnt vmcnt(0)" ::: "memory");   // drain before exit

    // ---- epilogue ----
    const int q = lane >> 4, cl = lane & 15;
#pragma unroll
    for (int am = 0; am < 8; am++) {
#pragma unroll
        for (int r = 0; r < 4; r++) {
            int srow = row0 + wrow * 128 + am * 16 + q * 4 + r;
            if (srow >= cnt) continue;
            if (OM == 0) {
#pragma unroll
                for (int fn = 0; fn < 4; fn++) {
                    int col = n0 + wcol * 64 + fn * 16 + cl;
                    float vv = acc[am][fn][r] + bias[(size_t)e * bstride + col];
                    if (ACT) vv = silu_f(vv);
                    outB[(size_t)(off + srow) * N + col] = (__bf16)vv;
                }
            } else {
                int grow = slot_row[e * NB + srow];
                float wsl = slot_w[e * NB + srow];
#pragma unroll
                for (int fn = 0; fn < 4; fn++) {
                    int col = n0 + wcol * 64 + fn * 16 + cl;
                    atomicAdd(&outF[(size_t)grow * NH + col], wsl * acc[am][fn][r]);
                }
            }
        }
    }
}

// ---------------------------------------------------------------------------
// Finalize IN-PLACE: out = fired ? a*(out/t) + (1-a)*x : x
// ---------------------------------------------------------------------------
__global__ __launch_bounds__(256) void k_final(
    const float* __restrict__ x,
    const float* __restrict__ row_total, const int* __restrict__ row_fired,
    const float* __restrict__ blend, float* __restrict__ out)
{
    int idx = blockIdx.x * 256 + threadIdx.x;
    int r = idx >> 8;
    int c = (idx & 255) << 2;
    float alpha = 1.f / (1.f + expf(-blend[0]));
    f32x4 cb = *(const f32x4*)(out + (size_t)r * NH + c);
    f32x4 xv = *(const f32x4*)(x + (size_t)r * NH + c);
    int fired = row_fired[r];
    float inv_t = fired ? (1.f / row_total[r]) : 0.f;
    f32x4 o;
#pragma unroll
    for (int j = 0; j < 4; j++)
        o[j] = fired ? (alpha * (cb[j] * inv_t) + (1.f - alpha) * xv[j]) : xv[j];
    *(f32x4*)&out[(size_t)r * NH + c] = o;
}

// ---------------------------------------------------------------------------
extern "C" void kernel_launch(void* const* d_in, const int* in_sizes, int n_in,
                              void* d_out, int out_size, void* d_ws, size_t ws_size,
                              hipStream_t stream)
{
    float* out_main = (float*)d_out;
    float* gw_out   = (float*)d_out + (size_t)NB * NH;

    static const long long EXP[11] = {
        (long long)NB * NH, (long long)NH * NG, NG, (long long)NG * NE, NE,
        (long long)NE * NH * NF, (long long)NE * NF,
        (long long)NE * NF * NH, (long long)NE * NH,
        (long long)NE * NH * NH, 1
    };
    bool ok = (n_in == 11);
    if (ok)
        for (int i = 0; i < 11; i++)
            if ((long long)in_sizes[i] != EXP[i]) { ok = false; break; }
    if (!ok) {
        k_sentinel<<<1, 1, 0, stream>>>((float*)d_out, 2000.f + n_in);
        return;
    }

    const float* x    = (const float*)d_in[0];
    const float* gw1  = (const float*)d_in[1];
    const float* gb1  = (const float*)d_in[2];
    const float* gw2  = (const float*)d_in[3];
    const float* gb2  = (const float*)d_in[4];
    const float* ew1  = (const float*)d_in[5];
    const float* eb1  = (const float*)d_in[6];
    const float* ew2  = (const float*)d_in[7];
    const float* eb2  = (const float*)d_in[8];
    const float* pw   = (const float*)d_in[9];
    const float* blnd = (const float*)d_in[10];

    // ---- workspace layout (identical to R11, proven fits) ----
    size_t need = 0;
    size_t off_meta   = need;   need += 512;
    size_t off_srow   = need;   need += (size_t)NE * NB * 4;
    size_t off_sw     = need;   need += (size_t)NE * NB * 4;
    size_t off_total  = need;   need += (size_t)NB * 4;
    size_t off_fired  = need;   need += (size_t)NB * 4;
    size_t off_hidden = need;   need += (size_t)NB * NG * 4;
    size_t a_xc  = need;
    size_t a_h1  = a_xc + ROWS * NH * 2;
    size_t a_h2  = a_h1 + ROWS * NF * 2;
    size_t a_w1  = a_h2 + ROWS * NH * 2;
    size_t a_w2  = a_w1 + (size_t)NE * NH * NF * 2;
    size_t a_wp  = a_w2 + (size_t)NE * NF * NH * 2;
    size_t need_A = a_wp + (size_t)NE * NH * NH * 2;

    char* ws = (char*)d_ws;
    int*   count     = (int*)(ws + off_meta);
    int*   offs      = count + 8;
    int*   slot_row  = (int*)(ws + off_srow);
    float* slot_w    = (float*)(ws + off_sw);
    float* row_total = (float*)(ws + off_total);
    int*   row_fired = (int*)(ws + off_fired);
    float* hidden    = (float*)(ws + off_hidden);

    if (ws_size < need_A) {
        k_sentinel<<<1, 1, 0, stream>>>((float*)d_out,
                                        1000.f + (float)(ws_size >> 20));
        return;
    }
    __bf16* Xc  = (__bf16*)(ws + a_xc);
    __bf16* H1  = (__bf16*)(ws + a_h1);
    __bf16* H2  = (__bf16*)(ws + a_h2);
    __bf16* Wt1 = (__bf16*)(ws + a_w1);
    __bf16* Wt2 = (__bf16*)(ws + a_w2);
    __bf16* Wtp = (__bf16*)(ws + a_wp);

    // allow 128 KiB dynamic LDS (idempotent; ignore errors)
    (void)hipFuncSetAttribute((const void*)&k_gemm8<1, 0>,
        hipFuncAttributeMaxDynamicSharedMemorySize, 131072);
    (void)hipFuncSetAttribute((const void*)&k_gemm8<0, 0>,
        hipFuncAttributeMaxDynamicSharedMemorySize, 131072);
    (void)hipFuncSetAttribute((const void*)&k_gemm8<0, 1>,
        hipFuncAttributeMaxDynamicSharedMemorySize, 131072);

    hipMemsetAsync(count, 0, 512, stream);
    hipMemsetAsync(out_main, 0, (size_t)NB * NH * 4, stream);

    k_gate<<<dim3(NG / 64, NB / 64), 256, 0, stream>>>(x, gw1, gb1, hidden);
    k_router<<<dim3(NB), 64, 0, stream>>>(hidden, gw2, gb2, gw_out,
                                          count, slot_row, slot_w, row_total, row_fired);
    k_offsets<<<1, 1, 0, stream>>>(count, offs);

    k_tconv<<<dim3(NF / 64, NH / 64, NE), 256, 0, stream>>>(ew1, Wt1, NH, NF);
    k_tconv<<<dim3(NH / 64, NF / 64, NE), 256, 0, stream>>>(ew2, Wt2, NF, NH);
    k_tconv<<<dim3(NH / 64, NH / 64, NE), 256, 0, stream>>>(pw,  Wtp, NH, NH);
    k_xc<<<dim3((int)MAXS), 256, 0, stream>>>(x, count, offs, slot_row, Xc);

    // FFN1: H1 = silu(Xc @ ew1 + eb1)      X = NF/256 = 16
    k_gemm8<1, 0><<<dim3(16 * NE, NB / 256), 512, 131072, stream>>>(
        Xc, NH, Wt1, (size_t)NH * NF, eb1, NF,
        H1, nullptr, NF, NH, 16, count, offs, slot_row, slot_w);
    // FFN2: H2 = H1 @ ew2 + eb2            X = NH/256 = 4
    k_gemm8<0, 0><<<dim3(4 * NE, NB / 256), 512, 131072, stream>>>(
        H1, NF, Wt2, (size_t)NF * NH, eb2, NH,
        H2, nullptr, NH, NF, 4, count, offs, slot_row, slot_w);
    // PROJ: out += slot_w * (H2 @ pw)      X = 4
    k_gemm8<0, 1><<<dim3(4 * NE, NB / 256), 512, 131072, stream>>>(
        H2, NH, Wtp, (size_t)NH * NH, eb2 /*unused*/, 0,
        nullptr, out_main, NH, NH, 4, count, offs, slot_row, slot_w);

    k_final<<<dim3(NB * NH / 1024), 256, 0, stream>>>(x, row_total,
                                                      row_fired, blnd, out_main);
}

// Round 16
// 542.360 us; speedup vs baseline: 1.1092x; 1.1005x over previous
//
#include <hip/hip_runtime.h>
#include <hip/hip_bf16.h>
#include <cmath>

constexpr int NB = 4096;   // batch
constexpr int NH = 1024;   // hidden
constexpr int NE = 8;      // experts
constexpr int NF = 4096;   // dff
constexpr int NG = 512;    // gate hidden (H/2)
constexpr float THRESH = 0.1f;
constexpr int PAD_ROWS = 128;
constexpr size_t MAXS = (size_t)2 * NB;        // <= 8192 routed slots
constexpr size_t ROWS = MAXS + PAD_ROWS;       // padded for tile overreach

// Established (rounds 0-15):
//   ALL inputs f32 C-order positional. d_out f32 [output(B,H) | gate_w(B,E)].
//   ws_size >= ~256 MiB. ~All top-2 pass threshold (S ~ 8175).
//   R11 gload_lds 128x128 GEMM = best structure (121 us FFN1); dbuf (R12),
//   supertile (R13), 8-phase 256^2 (R14/15, conflict-free) all slower.
//   This round: R11 GEMM restored; gate+tconv x3 fused into one concurrent
//   launch; tconv writes vectorized to bf16x4.

typedef float  f32x4  __attribute__((ext_vector_type(4)));
typedef __bf16 bf16x8 __attribute__((ext_vector_type(8)));
typedef __bf16 bf16x4 __attribute__((ext_vector_type(4)));

typedef __attribute__((address_space(1))) void gvoid_t;
typedef __attribute__((address_space(3))) void svoid_t;

__device__ __forceinline__ void gl_lds16(const void* g, void* l)
{
    __builtin_amdgcn_global_load_lds((gvoid_t*)g, (svoid_t*)l, 16, 0, 0);
}

__device__ __forceinline__ float silu_f(float v) { return v / (1.f + expf(-v)); }

__global__ void k_sentinel(float* out, float code)
{
    if (threadIdx.x == 0 && blockIdx.x == 0) out[0] = code;
}

// ---------------------------------------------------------------------------
// Fused pre-work: gate GEMM + 3 weight transpose/converts, one launch.
// Block-range decode; each block runs exactly one branch (uniform control).
//   [0, 512)            gate: hidden = silu(x @ gate_w1 + gate_b1), f32
//   [512, 8704)         tconv ew1 [e][NH][NF] -> Wt1 [e][NF][NH] bf16
//   [8704, 16896)       tconv ew2 [e][NF][NH] -> Wt2 [e][NH][NF] bf16
//   [16896, 18944)      tconv pw  [e][NH][NH] -> Wtp [e][NH][NH] bf16
// ---------------------------------------------------------------------------
__device__ __forceinline__ void tconv_body(
    const float* __restrict__ I, __bf16* __restrict__ O, int R, int C,
    int bx, int by, float* smem)
{
    // smem used as t[64][65]
    const int r0 = by * 64, c0 = bx * 64;
    const int tid = threadIdx.x;
#pragma unroll
    for (int i = 0; i < 16; i++) {
        int idx = tid + i * 256;
        int r = idx >> 6, c = idx & 63;
        smem[r * 65 + c] = I[(size_t)(r0 + r) * C + c0 + c];
    }
    __syncthreads();
    // vectorized write: thread -> (c_local, rq); 4 c-groups; bf16x4 per store
    const int cl = tid >> 4;      // 0..15
    const int rq = tid & 15;      // 0..15 -> rows rq*4..rq*4+3
#pragma unroll
    for (int i = 0; i < 4; i++) {
        int c = cl + i * 16;
        bf16x4 v;
#pragma unroll
        for (int j = 0; j < 4; j++)
            v[j] = (__bf16)smem[(rq * 4 + j) * 65 + c];
        *(bf16x4*)&O[(size_t)(c0 + c) * R + r0 + rq * 4] = v;
    }
}

__global__ __launch_bounds__(256) void k_prework(
    const float* __restrict__ x, const float* __restrict__ gw1,
    const float* __restrict__ gb1, float* __restrict__ hidden,
    const float* __restrict__ ew1, __bf16* __restrict__ Wt1,
    const float* __restrict__ ew2, __bf16* __restrict__ Wt2,
    const float* __restrict__ pw,  __bf16* __restrict__ Wtp)
{
    __shared__ float smem[64 * 65];   // 16.6 KB; gate carves As/Bs from it
    int id = blockIdx.x;

    if (id < 512) {
        // ---- gate GEMM (f32 exact, R11-proven body) ----
        float* As = smem;              // [16][68]
        float* Bs = smem + 16 * 68;    // [16][64]
        const int tid = threadIdx.x;
        const int r0 = (id >> 3) * 64, c0 = (id & 7) * 64;
        const int tx = tid & 15, ty = tid >> 4;
        float acc[4][4] = {};
        for (int k0 = 0; k0 < NH; k0 += 16) {
#pragma unroll
            for (int i = 0; i < 4; i++) {
                int e = tid + i * 256;
                int m = e >> 4, kk = e & 15;
                As[kk * 68 + m] = x[(size_t)(r0 + m) * NH + k0 + kk];
            }
#pragma unroll
            for (int i = 0; i < 4; i++) {
                int e = tid + i * 256;
                int kk = e >> 6, n = e & 63;
                Bs[kk * 64 + n] = gw1[(size_t)(k0 + kk) * NG + c0 + n];
            }
            __syncthreads();
#pragma unroll
            for (int kk = 0; kk < 16; kk++) {
                f32x4 a = *(const f32x4*)&As[kk * 68 + ty * 4];
                f32x4 b = *(const f32x4*)&Bs[kk * 64 + tx * 4];
#pragma unroll
                for (int i = 0; i < 4; i++)
#pragma unroll
                    for (int j = 0; j < 4; j++)
                        acc[i][j] = fmaf(a[i], b[j], acc[i][j]);
            }
            __syncthreads();
        }
#pragma unroll
        for (int i = 0; i < 4; i++) {
            int row = r0 + ty * 4 + i;
            f32x4 o;
#pragma unroll
            for (int j = 0; j < 4; j++)
                o[j] = silu_f(acc[i][j] + gb1[c0 + tx * 4 + j]);
            *(f32x4*)&hidden[(size_t)row * NG + c0 + tx * 4] = o;
        }
        return;
    }
    id -= 512;
    if (id < 8192) {      // tconv ew1: grid (64,16,8)
        int bx = id & 63, by = (id >> 6) & 15, e = id >> 10;
        tconv_body(ew1 + (size_t)e * NH * NF, Wt1 + (size_t)e * NH * NF,
                   NH, NF, bx, by, smem);
        return;
    }
    id -= 8192;
    if (id < 8192) {      // tconv ew2: grid (16,64,8)
        int bx = id & 15, by = (id >> 4) & 63, e = id >> 10;
        tconv_body(ew2 + (size_t)e * NF * NH, Wt2 + (size_t)e * NF * NH,
                   NF, NH, bx, by, smem);
        return;
    }
    id -= 8192;           // tconv pw: grid (16,16,8)
    {
        int bx = id & 15, by = (id >> 4) & 15, e = id >> 8;
        tconv_body(pw + (size_t)e * NH * NH, Wtp + (size_t)e * NH * NH,
                   NH, NH, bx, by, smem);
    }
}

// ---------------------------------------------------------------------------
// Router: softmax -> top2 -> threshold -> per-expert slot lists
// ---------------------------------------------------------------------------
__global__ __launch_bounds__(64) void k_router(
    const float* __restrict__ hidden, const float* __restrict__ w2,
    const float* __restrict__ b2, float* __restrict__ gw_out,
    int* __restrict__ count, int* __restrict__ slot_row,
    float* __restrict__ slot_w, float* __restrict__ row_total,
    int* __restrict__ row_fired)
{
    const int r = blockIdx.x;
    const int l = threadIdx.x;
    float pe[NE] = {};
    for (int k = l; k < NG; k += 64) {
        float h = hidden[(size_t)r * NG + k];
        const float* wr = w2 + (size_t)k * NE;
#pragma unroll
        for (int e = 0; e < NE; e++) pe[e] += h * wr[e];
    }
#pragma unroll
    for (int e = 0; e < NE; e++) {
#pragma unroll
        for (int m = 1; m < 64; m <<= 1) pe[e] += __shfl_xor(pe[e], m);
    }
    float logit[NE];
    float mx = -1e30f;
#pragma unroll
    for (int e = 0; e < NE; e++) { logit[e] = pe[e] + b2[e]; mx = fmaxf(mx, logit[e]); }
    float w[NE], s = 0.f;
#pragma unroll
    for (int e = 0; e < NE; e++) { w[e] = expf(logit[e] - mx); s += w[e]; }
    float inv = 1.f / s;
#pragma unroll
    for (int e = 0; e < NE; e++) w[e] *= inv;
    if (l < NE) gw_out[(size_t)r * NE + l] = w[l];

    int i1 = 0; float v1 = w[0];
#pragma unroll
    for (int e = 1; e < NE; e++) if (w[e] > v1) { v1 = w[e]; i1 = e; }
    int i2 = -1; float v2 = -1.f;
#pragma unroll
    for (int e = 0; e < NE; e++) if (e != i1 && w[e] > v2) { v2 = w[e]; i2 = e; }

    bool k1 = v1 > THRESH, k2 = v2 > THRESH;
    float total = (k1 ? v1 : 0.f) + (k2 ? v2 : 0.f);
    if (l == 0) {
        row_total[r] = total;
        row_fired[r] = (total > 0.f) ? 1 : 0;
        if (k1) { int p = atomicAdd(&count[i1], 1); slot_row[i1 * NB + p] = r; slot_w[i1 * NB + p] = v1; }
        if (k2) { int p = atomicAdd(&count[i2], 1); slot_row[i2 * NB + p] = r; slot_w[i2 * NB + p] = v2; }
    }
}

__global__ void k_offsets(const int* __restrict__ count, int* __restrict__ offs)
{
    if (threadIdx.x == 0 && blockIdx.x == 0) {
        int s = 0;
        for (int e = 0; e < NE; e++) { offs[e] = s; s += count[e]; }
    }
}

// ---------------------------------------------------------------------------
// Compacted bf16 x gather: Xc[slot] = bf16(x[slot_row])
// ---------------------------------------------------------------------------
__global__ __launch_bounds__(256) void k_xc(
    const float* __restrict__ x, const int* __restrict__ count,
    const int* __restrict__ offs, const int* __restrict__ slot_row,
    __bf16* __restrict__ Xc)
{
    const int s = blockIdx.x;
    int e = 0;
#pragma unroll
    for (int i = 1; i < NE; i++) if (s >= offs[i]) e = i;
    if (s >= offs[NE - 1] + count[NE - 1]) return;
    const int r = slot_row[e * NB + (s - offs[e])];
    const float* src = x + (size_t)r * NH;
    __bf16* dst = Xc + (size_t)s * NH;
    const int t = threadIdx.x;
    f32x4 v = *(const f32x4*)(src + t * 4);
    bf16x4 o;
#pragma unroll
    for (int j = 0; j < 4; j++) o[j] = (__bf16)v[j];
    *(bf16x4*)(dst + t * 4) = o;
}

// ---------------------------------------------------------------------------
// Routed GEMM — R11 proven version EXACT: 128x128 tile, single 32KiB buffer,
// gload_lds(16B) with source-side XOR swizzle, 2 barriers per K-step.
// Grid (X*NE, Y), e = bx/X, n0 = (bx%X)*128.
// OM: 0 = store bf16 compacted rows (+bias, silu if ACT), 1 = weighted
// f32 atomicAdd into d_out via slot lists.
// ---------------------------------------------------------------------------
template<int ACT, int OM>
__global__ __launch_bounds__(256) void k_gemm2(
    const __bf16* __restrict__ A, int lda,
    const __bf16* __restrict__ Wt, size_t wstride,
    const float* __restrict__ bias, int bstride,
    __bf16* __restrict__ outB, float* __restrict__ outF,
    int N, int Kd, int X,
    const int* __restrict__ count, const int* __restrict__ offs,
    const int* __restrict__ slot_row, const float* __restrict__ slot_w)
{
    const int bx = blockIdx.x;
    const int e  = bx / X;
    const int n0 = (bx % X) * 128;
    const int cnt = count[e];
    const int row0 = blockIdx.y * 128;
    if (row0 >= cnt) return;
    const int off = offs[e];
    const __bf16* W = Wt + (size_t)e * wstride;
    const int tid = threadIdx.x;
    const int lane = tid & 63, wid = tid >> 6;
    const int wm = (wid >> 1) * 64, wn = (wid & 1) * 64;
    const int arow0 = off + row0;

    __shared__ __align__(16) unsigned char sA[16384];  // [m][kslot] bf16
    __shared__ __align__(16) unsigned char sB[16384];  // [n][kslot] bf16

    f32x4 acc[4][4];
#pragma unroll
    for (int mi = 0; mi < 4; mi++)
#pragma unroll
        for (int ni = 0; ni < 4; ni++)
            acc[mi][ni] = (f32x4){0.f, 0.f, 0.f, 0.f};

    const int sub = lane >> 3;            // 0..7 row within chunk
    const int kcx = (lane & 7) ^ sub;     // source k-chunk (inverse swizzle)

    for (int k0 = 0; k0 < Kd; k0 += 64) {
#pragma unroll
        for (int i = 0; i < 4; i++) {
            int c = wid * 4 + i;          // chunk 0..15 (8 rows each)
            int row = c * 8 + sub;
            gl_lds16(A + (size_t)(arow0 + row) * lda + k0 + kcx * 8,
                     sA + c * 1024 + lane * 16);
        }
#pragma unroll
        for (int i = 0; i < 4; i++) {
            int c = wid * 4 + i;
            int n = c * 8 + sub;
            gl_lds16(W + (size_t)(n0 + n) * Kd + k0 + kcx * 8,
                     sB + c * 1024 + lane * 16);
        }
        __syncthreads();
#pragma unroll
        for (int ks = 0; ks < 2; ks++) {
            bf16x8 af[4], bfr[4];
            const int kb = ks * 64 + ((lane >> 4) << 4);
#pragma unroll
            for (int mi = 0; mi < 4; mi++) {
                int row = wm + mi * 16 + (lane & 15);
                af[mi] = *(const bf16x8*)(sA + row * 128 + (kb ^ ((row & 7) << 4)));
            }
#pragma unroll
            for (int ni = 0; ni < 4; ni++) {
                int row = wn + ni * 16 + (lane & 15);
                bfr[ni] = *(const bf16x8*)(sB + row * 128 + (kb ^ ((row & 7) << 4)));
            }
#pragma unroll
            for (int mi = 0; mi < 4; mi++)
#pragma unroll
                for (int ni = 0; ni < 4; ni++)
                    acc[mi][ni] = __builtin_amdgcn_mfma_f32_16x16x32_bf16(
                        af[mi], bfr[ni], acc[mi][ni], 0, 0, 0);
        }
        __syncthreads();
    }

    const int q = lane >> 4, cl = lane & 15;
#pragma unroll
    for (int mi = 0; mi < 4; mi++) {
#pragma unroll
        for (int r = 0; r < 4; r++) {
            int srow = row0 + wm + mi * 16 + q * 4 + r;
            if (srow >= cnt) continue;
            if (OM == 0) {
#pragma unroll
                for (int ni = 0; ni < 4; ni++) {
                    int col = n0 + wn + ni * 16 + cl;
                    float vv = acc[mi][ni][r] + bias[(size_t)e * bstride + col];
                    if (ACT) vv = silu_f(vv);
                    outB[(size_t)(off + srow) * N + col] = (__bf16)vv;
                }
            } else {
                int grow = slot_row[e * NB + srow];
                float wsl = slot_w[e * NB + srow];
#pragma unroll
                for (int ni = 0; ni < 4; ni++) {
                    int col = n0 + wn + ni * 16 + cl;
                    atomicAdd(&outF[(size_t)grow * NH + col], wsl * acc[mi][ni][r]);
                }
            }
        }
    }
}

// ---------------------------------------------------------------------------
// Finalize IN-PLACE: out = fired ? a*(out/t) + (1-a)*x : x
// ---------------------------------------------------------------------------
__global__ __launch_bounds__(256) void k_final(
    const float* __restrict__ x,
    const float* __restrict__ row_total, const int* __restrict__ row_fired,
    const float* __restrict__ blend, float* __restrict__ out)
{
    int idx = blockIdx.x * 256 + threadIdx.x;
    int r = idx >> 8;
    int c = (idx & 255) << 2;
    float alpha = 1.f / (1.f + expf(-blend[0]));
    f32x4 cb = *(const f32x4*)(out + (size_t)r * NH + c);
    f32x4 xv = *(const f32x4*)(x + (size_t)r * NH + c);
    int fired = row_fired[r];
    float inv_t = fired ? (1.f / row_total[r]) : 0.f;
    f32x4 o;
#pragma unroll
    for (int j = 0; j < 4; j++)
        o[j] = fired ? (alpha * (cb[j] * inv_t) + (1.f - alpha) * xv[j]) : xv[j];
    *(f32x4*)&out[(size_t)r * NH + c] = o;
}

// ---------------------------------------------------------------------------
extern "C" void kernel_launch(void* const* d_in, const int* in_sizes, int n_in,
                              void* d_out, int out_size, void* d_ws, size_t ws_size,
                              hipStream_t stream)
{
    float* out_main = (float*)d_out;
    float* gw_out   = (float*)d_out + (size_t)NB * NH;

    static const long long EXP[11] = {
        (long long)NB * NH, (long long)NH * NG, NG, (long long)NG * NE, NE,
        (long long)NE * NH * NF, (long long)NE * NF,
        (long long)NE * NF * NH, (long long)NE * NH,
        (long long)NE * NH * NH, 1
    };
    bool ok = (n_in == 11);
    if (ok)
        for (int i = 0; i < 11; i++)
            if ((long long)in_sizes[i] != EXP[i]) { ok = false; break; }
    if (!ok) {
        k_sentinel<<<1, 1, 0, stream>>>((float*)d_out, 2000.f + n_in);
        return;
    }

    const float* x    = (const float*)d_in[0];
    const float* gw1  = (const float*)d_in[1];
    const float* gb1  = (const float*)d_in[2];
    const float* gw2  = (const float*)d_in[3];
    const float* gb2  = (const float*)d_in[4];
    const float* ew1  = (const float*)d_in[5];
    const float* eb1  = (const float*)d_in[6];
    const float* ew2  = (const float*)d_in[7];
    const float* eb2  = (const float*)d_in[8];
    const float* pw   = (const float*)d_in[9];
    const float* blnd = (const float*)d_in[10];

    // ---- workspace layout (identical to R11, proven fits) ----
    size_t need = 0;
    size_t off_meta   = need;   need += 512;
    size_t off_srow   = need;   need += (size_t)NE * NB * 4;
    size_t off_sw     = need;   need += (size_t)NE * NB * 4;
    size_t off_total  = need;   need += (size_t)NB * 4;
    size_t off_fired  = need;   need += (size_t)NB * 4;
    size_t off_hidden = need;   need += (size_t)NB * NG * 4;
    size_t a_xc  = need;
    size_t a_h1  = a_xc + ROWS * NH * 2;
    size_t a_h2  = a_h1 + ROWS * NF * 2;
    size_t a_w1  = a_h2 + ROWS * NH * 2;
    size_t a_w2  = a_w1 + (size_t)NE * NH * NF * 2;
    size_t a_wp  = a_w2 + (size_t)NE * NF * NH * 2;
    size_t need_A = a_wp + (size_t)NE * NH * NH * 2;

    char* ws = (char*)d_ws;
    int*   count     = (int*)(ws + off_meta);
    int*   offs      = count + 8;
    int*   slot_row  = (int*)(ws + off_srow);
    float* slot_w    = (float*)(ws + off_sw);
    float* row_total = (float*)(ws + off_total);
    int*   row_fired = (int*)(ws + off_fired);
    float* hidden    = (float*)(ws + off_hidden);

    if (ws_size < need_A) {
        k_sentinel<<<1, 1, 0, stream>>>((float*)d_out,
                                        1000.f + (float)(ws_size >> 20));
        return;
    }
    __bf16* Xc  = (__bf16*)(ws + a_xc);
    __bf16* H1  = (__bf16*)(ws + a_h1);
    __bf16* H2  = (__bf16*)(ws + a_h2);
    __bf16* Wt1 = (__bf16*)(ws + a_w1);
    __bf16* Wt2 = (__bf16*)(ws + a_w2);
    __bf16* Wtp = (__bf16*)(ws + a_wp);

    hipMemsetAsync(count, 0, 512, stream);
    hipMemsetAsync(out_main, 0, (size_t)NB * NH * 4, stream);

    // Fused pre-work: gate + all 3 weight transposes, concurrent in 1 launch.
    k_prework<<<dim3(512 + 8192 + 8192 + 2048), 256, 0, stream>>>(
        x, gw1, gb1, hidden, ew1, Wt1, ew2, Wt2, pw, Wtp);

    k_router<<<dim3(NB), 64, 0, stream>>>(hidden, gw2, gb2, gw_out,
                                          count, slot_row, slot_w, row_total, row_fired);
    k_offsets<<<1, 1, 0, stream>>>(count, offs);
    k_xc<<<dim3((int)MAXS), 256, 0, stream>>>(x, count, offs, slot_row, Xc);

    // FFN1: H1 = silu(Xc @ ew1 + eb1)      X = NF/128 = 32
    k_gemm2<1, 0><<<dim3(32 * NE, NB / 128), 256, 0, stream>>>(
        Xc, NH, Wt1, (size_t)NH * NF, eb1, NF,
        H1, nullptr, NF, NH, 32, count, offs, slot_row, slot_w);
    // FFN2: H2 = H1 @ ew2 + eb2            X = NH/128 = 8
    k_gemm2<0, 0><<<dim3(8 * NE, NB / 128), 256, 0, stream>>>(
        H1, NF, Wt2, (size_t)NF * NH, eb2, NH,
        H2, nullptr, NH, NF, 8, count, offs, slot_row, slot_w);
    // PROJ: out += slot_w * (H2 @ pw)      X = 8
    k_gemm2<0, 1><<<dim3(8 * NE, NB / 128), 256, 0, stream>>>(
        H2, NH, Wtp, (size_t)NH * NH, eb2 /*unused*/, 0,
        nullptr, out_main, NH, NH, 8, count, offs, slot_row, slot_w);

    k_final<<<dim3(NB * NH / 1024), 256, 0, stream>>>(x, row_total,
                                                      row_fired, blnd, out_main);
}